// Round 8
// baseline (197.789 us; speedup 1.0000x reference)
//
#include <hip/hip_runtime.h>
#include <hip/hip_bf16.h>

// Problem shapes
#define B_SZ 64
#define T_PTS 300
#define N_SEG 299        // number of segments
#define VM 34            // 17*2
#define NPATH (B_SZ*VM)  // 2176
#define SIGC 120         // 3+9+27+81
#define FAN1 4080        // 34*120
#define H1 512
#define NOUT 155
#define CHUNK 3          // segments per global lane (128*3 = 384 >= 299)
#define KSPL 48          // gemm1 K-splits
#define KW 85            // k per wave (48*85 = 4080)
#define JPW 8            // gemm1 j-rows per wave

// ---------------------------------------------------------------------------
// Absorb one linear segment with increment d into state a1..a4.
// Horner-factored (segment signature = exp(d)): 189 VALU ops.
// ---------------------------------------------------------------------------
__device__ __forceinline__ void sig_append(float a1[3], float a2[9], float a3[27], float a4[81],
                                           float d0, float d1, float d2) {
  const float d[3] = {d0, d1, d2};

  // Level 4 (uses OLD a1,a2,a3)
  float Z[3], Y[9], X[27];
#pragma unroll
  for (int i = 0; i < 3; i++) Z[i] = fmaf(d[i], 1.0f / 24.0f, (1.0f / 6.0f) * a1[i]);
#pragma unroll
  for (int e = 0; e < 9; e++) Y[e] = fmaf(d[e % 3], Z[e / 3], 0.5f * a2[e]);
#pragma unroll
  for (int e = 0; e < 27; e++) X[e] = fmaf(d[e % 3], Y[e / 3], a3[e]);
#pragma unroll
  for (int e = 0; e < 81; e++) a4[e] = fmaf(d[e % 3], X[e / 3], a4[e]);

  // Level 3 (uses OLD a1,a2)
  float Z3[3], Y3[9];
#pragma unroll
  for (int i = 0; i < 3; i++) Z3[i] = fmaf(d[i], 1.0f / 6.0f, 0.5f * a1[i]);
#pragma unroll
  for (int e = 0; e < 9; e++) Y3[e] = fmaf(d[e % 3], Z3[e / 3], a2[e]);
#pragma unroll
  for (int e = 0; e < 27; e++) a3[e] = fmaf(d[e % 3], Y3[e / 3], a3[e]);

  // Level 2 (uses OLD a1)
  float Z2[3];
#pragma unroll
  for (int i = 0; i < 3; i++) Z2[i] = fmaf(d[i], 0.5f, a1[i]);
#pragma unroll
  for (int e = 0; e < 9; e++) a2[e] = fmaf(d[e % 3], Z2[e / 3], a2[e]);

#pragma unroll
  for (int i = 0; i < 3; i++) a1[i] += d[i];
}

// ---------------------------------------------------------------------------
// DPP row_shl:OFF cross-lane fetch (OFF in 1..15): lane i reads lane i+OFF
// within its 16-lane row; out-of-row lanes get 0 (= Chen identity).
// VERIFIED R3/R5/R6/R7.
// ---------------------------------------------------------------------------
template <int OFF>
__device__ __forceinline__ float lane_down(float x) {
  return __int_as_float(__builtin_amdgcn_update_dpp(
      0, __float_as_int(x), 0x100 + OFF /*row_shl:OFF*/, 0xF, 0xF, true));
}

// One row-local Chen-combine round: state <- state (x) fetched-state.
template <int OFF>
__device__ __forceinline__ void chen_round(float a1[3], float a2[9], float a3[27], float a4[81]) {
  float B1[3], B2[9], B3[27];
#pragma unroll
  for (int i = 0; i < 3; i++) B1[i] = lane_down<OFF>(a1[i]);
#pragma unroll
  for (int i = 0; i < 9; i++) B2[i] = lane_down<OFF>(a2[i]);
#pragma unroll
  for (int i = 0; i < 27; i++) B3[i] = lane_down<OFF>(a3[i]);

#pragma unroll
  for (int e = 0; e < 81; e++) {
    const float b4 = lane_down<OFF>(a4[e]);  // reads pre-update a4[e]
    float v = a4[e] + b4;
    v = fmaf(a3[e / 3], B1[e % 3], v);
    v = fmaf(a2[e / 9], B2[e % 9], v);
    v = fmaf(a1[e / 27], B3[e % 27], v);
    a4[e] = v;
  }
#pragma unroll
  for (int e = 0; e < 27; e++) {
    float v = a3[e] + B3[e];
    v = fmaf(a2[e / 3], B1[e % 3], v);
    v = fmaf(a1[e / 9], B2[e % 9], v);
    a3[e] = v;
  }
#pragma unroll
  for (int e = 0; e < 9; e++) a2[e] = fmaf(a1[e / 3], B1[e % 3], a2[e] + B2[e]);
#pragma unroll
  for (int i = 0; i < 3; i++) a1[i] += B1[i];
}

// ---------------------------------------------------------------------------
// One element of a Chen product C = A (x) B (flat 120-layout), element g.
// A = earlier-in-time block. Offsets VERIFIED in R7:
//   lvl2 e=g-3 : + A1[e/3]*B1[e%3]
//   lvl3 e=g-12: + A2[e/3]*B1[e%3] + A1[e/9]*B2[e%9]
//   lvl4 e=g-39: + A3[e/3]*B1[e%3] + A2[e/9]*B2[e%9] + A1[e/27]*B3[e%27]
// Branchless: unused terms have mask 0 and offset 0 (in-bounds).
// ---------------------------------------------------------------------------
__device__ __forceinline__ float chen_elem(const float* __restrict__ A,
                                           const float* __restrict__ Bv, int g) {
  int a1o = 0, b1o = 0, a2o = 0, b2o = 0, a3o = 0, b3o = 0;
  float m1 = 0.f, m2 = 0.f, m3 = 0.f;
  if (g >= 39) {
    const int e = g - 39;
    a1o = 12 + e / 3;  b1o = e % 3;       m1 = 1.f;
    a2o = 3 + e / 9;   b2o = 3 + e % 9;   m2 = 1.f;
    a3o = e / 27;      b3o = 12 + e % 27; m3 = 1.f;
  } else if (g >= 12) {
    const int e = g - 12;
    a1o = 3 + e / 3;   b1o = e % 3;       m1 = 1.f;
    a2o = e / 9;       b2o = 3 + e % 9;   m2 = 1.f;
  } else if (g >= 3) {
    const int e = g - 3;
    a1o = e / 3;       b1o = e % 3;       m1 = 1.f;
  }
  float c = A[g] + Bv[g];
  c = fmaf(m1 * A[a1o], Bv[b1o], c);
  c = fmaf(m2 * A[a2o], Bv[b2o], c);
  c = fmaf(m3 * A[a3o], Bv[b3o], c);
  return c;
}

// ---------------------------------------------------------------------------
// Kernel 1: signatures, reading inp directly. TWO waves per path now
// (2176 blocks x 128 threads = 4352 waves = 4.25/SIMD grid, resident count
// pinned to 3/SIMD by amdgpu_waves_per_eu(3); the old 1-wave-per-block grid
// was stuck at 2.125/SIMD and stall-bound — R1: VALUBusy 36%, occ 11%).
// Phases:
//   1) 128 global lanes x 3 Horner appends (lane gl: segs [3gl, 3gl+3),
//      clamped; invalid segs get d=0 = identity).
//   2) Rounds 1,2,4,8: DPP row-local Kogge-Stone suffix scan -> 8 row
//      leaders across the 2 waves hold the 8 sub-signatures S0..S7
//      (S_r = segs [48r, 48r+48)).
//   3) Cooperative LDS tree (R7-verified chen_elem, one extra level):
//      leaders write S0..S7; 128 threads compute S0S1,S2S3,S4S5,S6S7 ->
//      (S0..S3),(S4..S7) -> full signature, stored straight to St.
// First 256 blocks zero their 128 ht floats (b1 folded into gemm2).
// Output TRANSPOSED: St[k][b], k = vm*120 + c.
// ---------------------------------------------------------------------------
__global__ __launch_bounds__(128)
__attribute__((amdgpu_waves_per_eu(3)))
void sig_kernel(const float* __restrict__ inp, float* __restrict__ St,
                float* __restrict__ ht) {
  __shared__ float smem[14 * 128];  // S0..S7 | L1 x4 | L2 x2   (7 KB)
  const int tid = threadIdx.x;
  const int lane = tid & 63;
  const int wv = tid >> 6;          // wave in block: 0,1
  const int p = blockIdx.x;         // 2176 paths
  if (p < 256) ht[(size_t)p * 128 + tid] = 0.0f;  // zero-init for gemm1 atomics

  const int b = p / VM;
  const int vm = p - b * VM;
  const int gl = wv * 64 + lane;    // global lane 0..127
  const int t0 = gl * CHUNK;

  // inp element ((b*3+c)*300 + t)*34 + vm; channel stride 10200, t stride 34.
  const float* base = inp + (size_t)b * 3 * T_PTS * VM + vm;

  float a1[3], a2[9], a3[27], a4[81];
#pragma unroll
  for (int i = 0; i < 3; i++) a1[i] = 0.f;
#pragma unroll
  for (int i = 0; i < 9; i++) a2[i] = 0.f;
#pragma unroll
  for (int i = 0; i < 27; i++) a3[i] = 0.f;
#pragma unroll
  for (int i = 0; i < 81; i++) a4[i] = 0.f;

  const int tp0 = t0 < N_SEG ? t0 : N_SEG;
  float x0 = base[0 * T_PTS * VM + tp0 * VM];
  float x1 = base[1 * T_PTS * VM + tp0 * VM];
  float x2 = base[2 * T_PTS * VM + tp0 * VM];
#pragma unroll
  for (int s = 0; s < CHUNK; s++) {
    const int tn = (t0 + s + 1) < N_SEG ? (t0 + s + 1) : N_SEG;
    const float y0 = base[0 * T_PTS * VM + tn * VM];
    const float y1 = base[1 * T_PTS * VM + tn * VM];
    const float y2 = base[2 * T_PTS * VM + tn * VM];
    const bool valid = (t0 + s) < N_SEG;
    const float d0 = valid ? (y0 - x0) : 0.0f;
    const float d1 = valid ? (y1 - x1) : 0.0f;
    const float d2 = valid ? (y2 - x2) : 0.0f;
    sig_append(a1, a2, a3, a4, d0, d1, d2);
    x0 = y0; x1 = y1; x2 = y2;
  }

  // Row-local suffix Chen product (16-lane Kogge-Stone via DPP).
  chen_round<1>(a1, a2, a3, a4);
  chen_round<2>(a1, a2, a3, a4);
  chen_round<4>(a1, a2, a3, a4);
  chen_round<8>(a1, a2, a3, a4);

  // ---- Phase 3: cooperative LDS tree over the 8 leaders ----
  if ((lane & 15) == 0) {
    float* s = smem + (wv * 4 + (lane >> 4)) * 128;  // rows 0..7, time order
#pragma unroll
    for (int i = 0; i < 3; i++) s[i] = a1[i];
#pragma unroll
    for (int i = 0; i < 9; i++) s[3 + i] = a2[i];
#pragma unroll
    for (int i = 0; i < 27; i++) s[12 + i] = a3[i];
#pragma unroll
    for (int i = 0; i < 81; i++) s[39 + i] = a4[i];
  }
  __syncthreads();

  // Level 1: (S0,S1)->8  (S2,S3)->9  (S4,S5)->10  (S6,S7)->11
  {
    const int pr = tid >> 5;        // 0..3
    const int i0 = tid & 31;
    const float* A = smem + (2 * pr) * 128;
    const float* Bv = smem + (2 * pr + 1) * 128;
    float* D = smem + (8 + pr) * 128;
#pragma unroll
    for (int s = 0; s < 4; s++) {
      const int g = i0 + 32 * s;
      if (g < SIGC) D[g] = chen_elem(A, Bv, g);
    }
  }
  __syncthreads();

  // Level 2: (8,9)->12  (10,11)->13
  {
    const int pr = tid >> 6;        // 0..1
    const int i0 = tid & 63;
    const float* A = smem + (8 + 2 * pr) * 128;
    const float* Bv = smem + (8 + 2 * pr + 1) * 128;
    float* D = smem + (12 + pr) * 128;
#pragma unroll
    for (int s = 0; s < 2; s++) {
      const int g = i0 + 64 * s;
      if (g < SIGC) D[g] = chen_elem(A, Bv, g);
    }
  }
  __syncthreads();

  // Level 3: (12,13) -> St[(vm*120+g)*64 + b]
  if (tid < SIGC) {
    const float v = chen_elem(smem + 12 * 128, smem + 13 * 128, tid);
    St[(size_t)(vm * SIGC + tid) * 64 + b] = v;
  }
}

// ---------------------------------------------------------------------------
// Kernel 2: ht[j][b] += sum_k St[k][b] * W1[j][k].  lane = b (M=64=wave).
// 3072 waves: 48 K-splits (85 k each) x 64 j-groups (8 j each). sv[85]
// register-resident (static indices); W1 rows are wave-uniform streams
// (scalar loads). 8 independent FMA chains. Coalesced atomicAdd epilogue
// onto the zero-initialized ht (48 adds/element, order-independent).
// ---------------------------------------------------------------------------
__global__ __launch_bounds__(256) void gemm1_kernel(const float* __restrict__ St,
                                                    const float* __restrict__ W1,
                                                    float* __restrict__ ht) {
  const int lane = threadIdx.x & 63;
  int wave_id = (blockIdx.x * 256 + threadIdx.x) >> 6;        // 0..3071
  wave_id = __builtin_amdgcn_readfirstlane(wave_id);          // force SGPR
  const int ks = wave_id >> 6;    // 0..47  (k-range of 85)
  const int jg = wave_id & 63;    // 0..63  (8 j's each)
  const int k0 = ks * KW;

  const float* stp = St + (size_t)k0 * 64 + lane;
  const float* w[JPW];
#pragma unroll
  for (int r = 0; r < JPW; r++) w[r] = W1 + (size_t)(jg * JPW + r) * FAN1 + k0;  // uniform -> s_load

  float sv[KW];
#pragma unroll
  for (int i = 0; i < KW; i++) sv[i] = stp[(size_t)i * 64];

  float acc[JPW];
#pragma unroll
  for (int r = 0; r < JPW; r++) acc[r] = 0.f;

#pragma unroll
  for (int i = 0; i < KW; i++) {
#pragma unroll
    for (int r = 0; r < JPW; r++) acc[r] = fmaf(sv[i], w[r][i], acc[r]);
  }

  float* hp = ht + (size_t)(jg * JPW) * 64 + lane;
#pragma unroll
  for (int r = 0; r < JPW; r++) atomicAdd(hp + r * 64, acc[r]);
}

// ---------------------------------------------------------------------------
// Kernel 3: out[b][j] = sum_k2 (ht[k2][b] + b1[k2]) * W2[j][k2] + b2[j].
// lane = b. Block = one j; 4 waves split k2 (128 each). The b1 fold is a
// second wave-uniform FMA chain in the same loop; red[w] = acc + accb so
// the LDS reduce also sums the b1·W2[j] correction. Single non-atomic store.
// ---------------------------------------------------------------------------
__global__ __launch_bounds__(256) void gemm2_kernel(const float* __restrict__ ht,
                                                    const float* __restrict__ W2,
                                                    const float* __restrict__ b1,
                                                    const float* __restrict__ b2,
                                                    float* __restrict__ out) {
  const int j = blockIdx.x;              // 0..154
  const int lane = threadIdx.x & 63;
  int w = threadIdx.x >> 6;              // 0..3
  w = __builtin_amdgcn_readfirstlane(w);
  __shared__ float red[4][64];

  const float* htp = ht + (size_t)(w * 128) * 64 + lane;
  const float* w2r = W2 + (size_t)j * H1 + w * 128;  // uniform -> s_load
  const float* b1r = b1 + w * 128;                   // uniform -> s_load
  float acc = 0.f, accb = 0.f;
#pragma unroll 8
  for (int k = 0; k < 128; k++) {
    const float wv = w2r[k];
    acc = fmaf(wv, htp[(size_t)k * 64], acc);
    accb = fmaf(wv, b1r[k], accb);
  }

  red[w][lane] = acc + accb;
  __syncthreads();
  if (threadIdx.x < 64) {
    const float tot = red[0][lane] + red[1][lane] + red[2][lane] + red[3][lane];
    out[(size_t)lane * NOUT + j] = tot + b2[j];
  }
}

// ---------------------------------------------------------------------------
extern "C" void kernel_launch(void* const* d_in, const int* in_sizes, int n_in,
                              void* d_out, int out_size, void* d_ws, size_t ws_size,
                              hipStream_t stream) {
  const float* inp = (const float*)d_in[0];  // (64,3,300,17,2)
  const float* W1  = (const float*)d_in[1];  // (512,4080)
  const float* b1  = (const float*)d_in[2];  // (512,)
  const float* W2  = (const float*)d_in[3];  // (155,512)
  const float* b2  = (const float*)d_in[4];  // (155,)
  float* out = (float*)d_out;                // (64,155)

  // ws layout (floats): St | ht   (~1.2 MB total)
  float* St = (float*)d_ws;                  // 4080*64
  float* ht = St + (size_t)FAN1 * 64;        // 512*64

  sig_kernel<<<NPATH, 128, 0, stream>>>(inp, St, ht);
  gemm1_kernel<<<KSPL * 64 / 4, 256, 0, stream>>>(St, W1, ht);
  gemm2_kernel<<<NOUT, 256, 0, stream>>>(ht, W2, b1, b2, out);
}

// Round 9
// 125.248 us; speedup vs baseline: 1.5792x; 1.5792x over previous
//
#include <hip/hip_runtime.h>
#include <hip/hip_bf16.h>

// Problem shapes
#define B_SZ 64
#define T_PTS 300
#define N_SEG 299        // number of segments
#define VM 34            // 17*2
#define NPATH (B_SZ*VM)  // 2176
#define SIGC 120         // 3+9+27+81
#define FAN1 4080        // 34*120
#define H1 512
#define NOUT 155
#define CHUNK 3          // segments per global lane (128*3 = 384 >= 299)
#define KSPL 48          // gemm1 K-splits
#define KW 85            // k per wave (48*85 = 4080)
#define JPW 8            // gemm1 j-rows per wave
#define SROW 132         // LDS row stride (floats): 132%32=4 banks offset/row
                         // -> the 8 leaders' parallel writes are conflict-free
                         // (R8 measured 1.03M SQ_LDS_BANK_CONFLICT at stride 128)

// ---------------------------------------------------------------------------
// Absorb one linear segment with increment d into state a1..a4.
// Horner-factored (segment signature = exp(d)): 189 VALU ops.
// ---------------------------------------------------------------------------
__device__ __forceinline__ void sig_append(float a1[3], float a2[9], float a3[27], float a4[81],
                                           float d0, float d1, float d2) {
  const float d[3] = {d0, d1, d2};

  // Level 4 (uses OLD a1,a2,a3)
  float Z[3], Y[9], X[27];
#pragma unroll
  for (int i = 0; i < 3; i++) Z[i] = fmaf(d[i], 1.0f / 24.0f, (1.0f / 6.0f) * a1[i]);
#pragma unroll
  for (int e = 0; e < 9; e++) Y[e] = fmaf(d[e % 3], Z[e / 3], 0.5f * a2[e]);
#pragma unroll
  for (int e = 0; e < 27; e++) X[e] = fmaf(d[e % 3], Y[e / 3], a3[e]);
#pragma unroll
  for (int e = 0; e < 81; e++) a4[e] = fmaf(d[e % 3], X[e / 3], a4[e]);

  // Level 3 (uses OLD a1,a2)
  float Z3[3], Y3[9];
#pragma unroll
  for (int i = 0; i < 3; i++) Z3[i] = fmaf(d[i], 1.0f / 6.0f, 0.5f * a1[i]);
#pragma unroll
  for (int e = 0; e < 9; e++) Y3[e] = fmaf(d[e % 3], Z3[e / 3], a2[e]);
#pragma unroll
  for (int e = 0; e < 27; e++) a3[e] = fmaf(d[e % 3], Y3[e / 3], a3[e]);

  // Level 2 (uses OLD a1)
  float Z2[3];
#pragma unroll
  for (int i = 0; i < 3; i++) Z2[i] = fmaf(d[i], 0.5f, a1[i]);
#pragma unroll
  for (int e = 0; e < 9; e++) a2[e] = fmaf(d[e % 3], Z2[e / 3], a2[e]);

#pragma unroll
  for (int i = 0; i < 3; i++) a1[i] += d[i];
}

// ---------------------------------------------------------------------------
// DPP row_shl:OFF cross-lane fetch (OFF in 1..15): lane i reads lane i+OFF
// within its 16-lane row; out-of-row lanes get 0 (= Chen identity).
// VERIFIED R3/R5/R6/R7.
// ---------------------------------------------------------------------------
template <int OFF>
__device__ __forceinline__ float lane_down(float x) {
  return __int_as_float(__builtin_amdgcn_update_dpp(
      0, __float_as_int(x), 0x100 + OFF /*row_shl:OFF*/, 0xF, 0xF, true));
}

// One row-local Chen-combine round: state <- state (x) fetched-state.
template <int OFF>
__device__ __forceinline__ void chen_round(float a1[3], float a2[9], float a3[27], float a4[81]) {
  float B1[3], B2[9], B3[27];
#pragma unroll
  for (int i = 0; i < 3; i++) B1[i] = lane_down<OFF>(a1[i]);
#pragma unroll
  for (int i = 0; i < 9; i++) B2[i] = lane_down<OFF>(a2[i]);
#pragma unroll
  for (int i = 0; i < 27; i++) B3[i] = lane_down<OFF>(a3[i]);

#pragma unroll
  for (int e = 0; e < 81; e++) {
    const float b4 = lane_down<OFF>(a4[e]);  // reads pre-update a4[e]
    float v = a4[e] + b4;
    v = fmaf(a3[e / 3], B1[e % 3], v);
    v = fmaf(a2[e / 9], B2[e % 9], v);
    v = fmaf(a1[e / 27], B3[e % 27], v);
    a4[e] = v;
  }
#pragma unroll
  for (int e = 0; e < 27; e++) {
    float v = a3[e] + B3[e];
    v = fmaf(a2[e / 3], B1[e % 3], v);
    v = fmaf(a1[e / 9], B2[e % 9], v);
    a3[e] = v;
  }
#pragma unroll
  for (int e = 0; e < 9; e++) a2[e] = fmaf(a1[e / 3], B1[e % 3], a2[e] + B2[e]);
#pragma unroll
  for (int i = 0; i < 3; i++) a1[i] += B1[i];
}

// ---------------------------------------------------------------------------
// One element of a Chen product C = A (x) B (flat 120-layout), element g.
// A = earlier-in-time block. Offsets VERIFIED in R7.
// ---------------------------------------------------------------------------
__device__ __forceinline__ float chen_elem(const float* __restrict__ A,
                                           const float* __restrict__ Bv, int g) {
  int a1o = 0, b1o = 0, a2o = 0, b2o = 0, a3o = 0, b3o = 0;
  float m1 = 0.f, m2 = 0.f, m3 = 0.f;
  if (g >= 39) {
    const int e = g - 39;
    a1o = 12 + e / 3;  b1o = e % 3;       m1 = 1.f;
    a2o = 3 + e / 9;   b2o = 3 + e % 9;   m2 = 1.f;
    a3o = e / 27;      b3o = 12 + e % 27; m3 = 1.f;
  } else if (g >= 12) {
    const int e = g - 12;
    a1o = 3 + e / 3;   b1o = e % 3;       m1 = 1.f;
    a2o = e / 9;       b2o = 3 + e % 9;   m2 = 1.f;
  } else if (g >= 3) {
    const int e = g - 3;
    a1o = e / 3;       b1o = e % 3;       m1 = 1.f;
  }
  float c = A[g] + Bv[g];
  c = fmaf(m1 * A[a1o], Bv[b1o], c);
  c = fmaf(m2 * A[a2o], Bv[b2o], c);
  c = fmaf(m3 * A[a3o], Bv[b3o], c);
  return c;
}

// ---------------------------------------------------------------------------
// Kernel 1: signatures, reading inp directly. TWO waves per path
// (2176 blocks x 128 threads = 4352 waves = 4.25/SIMD grid; at ~136 VGPR
// the HW naturally fits 3 waves/SIMD).
// R8 post-mortem: amdgpu_waves_per_eu(3) forced the allocator to SPILL the
// 120-float state to scratch (VGPR 136->84, ~400 MB HBM scratch traffic,
// sig 138 us). waves_per_eu(1) = no occupancy floor, no forced spill; let
// VGPR pressure set residency. Do not raise this attribute again.
// Phases:
//   1) 128 global lanes x 3 Horner appends (lane gl: segs [3gl, 3gl+3),
//      clamped; invalid segs get d=0 = identity).
//   2) Rounds 1,2,4,8: DPP row-local Kogge-Stone suffix scan -> 8 row
//      leaders hold the 8 sub-signatures S0..S7 (S_r = segs [48r,48r+48)).
//   3) Cooperative LDS tree (R7-verified chen_elem): leaders write S0..S7;
//      128 threads compute 4 -> 2 -> 1 products; final stored straight
//      to St. LDS rows stride SROW=132 (bank-conflict-free leader writes).
// First 256 blocks zero their 128 ht floats (b1 folded into gemm2).
// Output TRANSPOSED: St[k][b], k = vm*120 + c.
// ---------------------------------------------------------------------------
__global__ __launch_bounds__(128)
__attribute__((amdgpu_waves_per_eu(1)))
void sig_kernel(const float* __restrict__ inp, float* __restrict__ St,
                float* __restrict__ ht) {
  __shared__ float smem[14 * SROW];  // S0..S7 | L1 x4 | L2 x2   (~7.4 KB)
  const int tid = threadIdx.x;
  const int lane = tid & 63;
  const int wv = tid >> 6;          // wave in block: 0,1
  const int p = blockIdx.x;         // 2176 paths
  if (p < 256) ht[(size_t)p * 128 + tid] = 0.0f;  // zero-init for gemm1 atomics

  const int b = p / VM;
  const int vm = p - b * VM;
  const int gl = wv * 64 + lane;    // global lane 0..127
  const int t0 = gl * CHUNK;

  // inp element ((b*3+c)*300 + t)*34 + vm; channel stride 10200, t stride 34.
  const float* base = inp + (size_t)b * 3 * T_PTS * VM + vm;

  float a1[3], a2[9], a3[27], a4[81];
#pragma unroll
  for (int i = 0; i < 3; i++) a1[i] = 0.f;
#pragma unroll
  for (int i = 0; i < 9; i++) a2[i] = 0.f;
#pragma unroll
  for (int i = 0; i < 27; i++) a3[i] = 0.f;
#pragma unroll
  for (int i = 0; i < 81; i++) a4[i] = 0.f;

  const int tp0 = t0 < N_SEG ? t0 : N_SEG;
  float x0 = base[0 * T_PTS * VM + tp0 * VM];
  float x1 = base[1 * T_PTS * VM + tp0 * VM];
  float x2 = base[2 * T_PTS * VM + tp0 * VM];
#pragma unroll
  for (int s = 0; s < CHUNK; s++) {
    const int tn = (t0 + s + 1) < N_SEG ? (t0 + s + 1) : N_SEG;
    const float y0 = base[0 * T_PTS * VM + tn * VM];
    const float y1 = base[1 * T_PTS * VM + tn * VM];
    const float y2 = base[2 * T_PTS * VM + tn * VM];
    const bool valid = (t0 + s) < N_SEG;
    const float d0 = valid ? (y0 - x0) : 0.0f;
    const float d1 = valid ? (y1 - x1) : 0.0f;
    const float d2 = valid ? (y2 - x2) : 0.0f;
    sig_append(a1, a2, a3, a4, d0, d1, d2);
    x0 = y0; x1 = y1; x2 = y2;
  }

  // Row-local suffix Chen product (16-lane Kogge-Stone via DPP).
  chen_round<1>(a1, a2, a3, a4);
  chen_round<2>(a1, a2, a3, a4);
  chen_round<4>(a1, a2, a3, a4);
  chen_round<8>(a1, a2, a3, a4);

  // ---- Phase 3: cooperative LDS tree over the 8 leaders ----
  if ((lane & 15) == 0) {
    float* s = smem + (wv * 4 + (lane >> 4)) * SROW;  // rows 0..7, time order
#pragma unroll
    for (int i = 0; i < 3; i++) s[i] = a1[i];
#pragma unroll
    for (int i = 0; i < 9; i++) s[3 + i] = a2[i];
#pragma unroll
    for (int i = 0; i < 27; i++) s[12 + i] = a3[i];
#pragma unroll
    for (int i = 0; i < 81; i++) s[39 + i] = a4[i];
  }
  __syncthreads();

  // Level 1: (S0,S1)->8  (S2,S3)->9  (S4,S5)->10  (S6,S7)->11
  {
    const int pr = tid >> 5;        // 0..3
    const int i0 = tid & 31;
    const float* A = smem + (2 * pr) * SROW;
    const float* Bv = smem + (2 * pr + 1) * SROW;
    float* D = smem + (8 + pr) * SROW;
#pragma unroll
    for (int s = 0; s < 4; s++) {
      const int g = i0 + 32 * s;
      if (g < SIGC) D[g] = chen_elem(A, Bv, g);
    }
  }
  __syncthreads();

  // Level 2: (8,9)->12  (10,11)->13
  {
    const int pr = tid >> 6;        // 0..1
    const int i0 = tid & 63;
    const float* A = smem + (8 + 2 * pr) * SROW;
    const float* Bv = smem + (8 + 2 * pr + 1) * SROW;
    float* D = smem + (12 + pr) * SROW;
#pragma unroll
    for (int s = 0; s < 2; s++) {
      const int g = i0 + 64 * s;
      if (g < SIGC) D[g] = chen_elem(A, Bv, g);
    }
  }
  __syncthreads();

  // Level 3: (12,13) -> St[(vm*120+g)*64 + b]
  if (tid < SIGC) {
    const float v = chen_elem(smem + 12 * SROW, smem + 13 * SROW, tid);
    St[(size_t)(vm * SIGC + tid) * 64 + b] = v;
  }
}

// ---------------------------------------------------------------------------
// Kernel 2: ht[j][b] += sum_k St[k][b] * W1[j][k].  lane = b (M=64=wave).
// 3072 waves: 48 K-splits (85 k each) x 64 j-groups (8 j each). sv[85]
// register-resident (static indices); W1 rows are wave-uniform streams
// (scalar loads). 8 independent FMA chains. Coalesced atomicAdd epilogue
// onto the zero-initialized ht (48 adds/element, order-independent).
// ---------------------------------------------------------------------------
__global__ __launch_bounds__(256) void gemm1_kernel(const float* __restrict__ St,
                                                    const float* __restrict__ W1,
                                                    float* __restrict__ ht) {
  const int lane = threadIdx.x & 63;
  int wave_id = (blockIdx.x * 256 + threadIdx.x) >> 6;        // 0..3071
  wave_id = __builtin_amdgcn_readfirstlane(wave_id);          // force SGPR
  const int ks = wave_id >> 6;    // 0..47  (k-range of 85)
  const int jg = wave_id & 63;    // 0..63  (8 j's each)
  const int k0 = ks * KW;

  const float* stp = St + (size_t)k0 * 64 + lane;
  const float* w[JPW];
#pragma unroll
  for (int r = 0; r < JPW; r++) w[r] = W1 + (size_t)(jg * JPW + r) * FAN1 + k0;  // uniform -> s_load

  float sv[KW];
#pragma unroll
  for (int i = 0; i < KW; i++) sv[i] = stp[(size_t)i * 64];

  float acc[JPW];
#pragma unroll
  for (int r = 0; r < JPW; r++) acc[r] = 0.f;

#pragma unroll
  for (int i = 0; i < KW; i++) {
#pragma unroll
    for (int r = 0; r < JPW; r++) acc[r] = fmaf(sv[i], w[r][i], acc[r]);
  }

  float* hp = ht + (size_t)(jg * JPW) * 64 + lane;
#pragma unroll
  for (int r = 0; r < JPW; r++) atomicAdd(hp + r * 64, acc[r]);
}

// ---------------------------------------------------------------------------
// Kernel 3: out[b][j] = sum_k2 (ht[k2][b] + b1[k2]) * W2[j][k2] + b2[j].
// lane = b. Block = one j; 4 waves split k2 (128 each). The b1 fold is a
// second wave-uniform FMA chain in the same loop; red[w] = acc + accb so
// the LDS reduce also sums the b1·W2[j] correction. Single non-atomic store.
// ---------------------------------------------------------------------------
__global__ __launch_bounds__(256) void gemm2_kernel(const float* __restrict__ ht,
                                                    const float* __restrict__ W2,
                                                    const float* __restrict__ b1,
                                                    const float* __restrict__ b2,
                                                    float* __restrict__ out) {
  const int j = blockIdx.x;              // 0..154
  const int lane = threadIdx.x & 63;
  int w = threadIdx.x >> 6;              // 0..3
  w = __builtin_amdgcn_readfirstlane(w);
  __shared__ float red[4][64];

  const float* htp = ht + (size_t)(w * 128) * 64 + lane;
  const float* w2r = W2 + (size_t)j * H1 + w * 128;  // uniform -> s_load
  const float* b1r = b1 + w * 128;                   // uniform -> s_load
  float acc = 0.f, accb = 0.f;
#pragma unroll 8
  for (int k = 0; k < 128; k++) {
    const float wv = w2r[k];
    acc = fmaf(wv, htp[(size_t)k * 64], acc);
    accb = fmaf(wv, b1r[k], accb);
  }

  red[w][lane] = acc + accb;
  __syncthreads();
  if (threadIdx.x < 64) {
    const float tot = red[0][lane] + red[1][lane] + red[2][lane] + red[3][lane];
    out[(size_t)lane * NOUT + j] = tot + b2[j];
  }
}

// ---------------------------------------------------------------------------
extern "C" void kernel_launch(void* const* d_in, const int* in_sizes, int n_in,
                              void* d_out, int out_size, void* d_ws, size_t ws_size,
                              hipStream_t stream) {
  const float* inp = (const float*)d_in[0];  // (64,3,300,17,2)
  const float* W1  = (const float*)d_in[1];  // (512,4080)
  const float* b1  = (const float*)d_in[2];  // (512,)
  const float* W2  = (const float*)d_in[3];  // (155,512)
  const float* b2  = (const float*)d_in[4];  // (155,)
  float* out = (float*)d_out;                // (64,155)

  // ws layout (floats): St | ht   (~1.2 MB total)
  float* St = (float*)d_ws;                  // 4080*64
  float* ht = St + (size_t)FAN1 * 64;        // 512*64

  sig_kernel<<<NPATH, 128, 0, stream>>>(inp, St, ht);
  gemm1_kernel<<<KSPL * 64 / 4, 256, 0, stream>>>(St, W1, ht);
  gemm2_kernel<<<NOUT, 256, 0, stream>>>(ht, W2, b1, b2, out);
}

// Round 10
// 115.657 us; speedup vs baseline: 1.7101x; 1.0829x over previous
//
#include <hip/hip_runtime.h>
#include <hip/hip_bf16.h>

// Problem shapes
#define B_SZ 64
#define T_PTS 300
#define N_SEG 299        // number of segments
#define VM 34            // 17*2
#define NPATH (B_SZ*VM)  // 2176
#define SIGC 120         // 3+9+27+81
#define FAN1 4080        // 34*120
#define H1 512
#define NOUT 155
#define CHUNK 5          // segments per lane (64*5=320 >= 299, 7% waste)
#define KSPL 48          // gemm1 K-splits
#define KW 85            // k per wave (48*85 = 4080)
#define JPW 8            // gemm1 j-rows per wave

// ---------------------------------------------------------------------------
// SESSION JOURNAL (why this exact configuration):
//  R6  = this config: 114.2 us total (best band, tied w/ R3's 113.96).
//  R7  coop-LDS-tree combine: 115.5 (neutral) -> shfl butterflies kept.
//  R8  amdgpu_waves_per_eu(3): allocator SPILLED the 120-float state
//      (VGPR 136->84, 400 MB scratch HBM, sig 138 us). NEVER raise it.
//  R9  2-wave/path split: sig 44.5 us vs ~33 here (+25% issue count from
//      chunk padding, +33% strided loads, 3 barriers). Occupancy cannot be
//      bought for this kernel: state too big to split without spill or
//      redundant work. 1 wave/path + CHUNK 5 is the measured optimum.
//  R4  v_permlane16/32_swap butterflies: WRONG DIRECTION (absmax 497).
//      Do not reintroduce without an isolated semantics probe.
// ---------------------------------------------------------------------------

// ---------------------------------------------------------------------------
// Absorb one linear segment with increment d into state a1..a4.
// Horner-factored (segment signature = exp(d)): 189 VALU ops vs ~480 naive.
// ---------------------------------------------------------------------------
__device__ __forceinline__ void sig_append(float a1[3], float a2[9], float a3[27], float a4[81],
                                           float d0, float d1, float d2) {
  const float d[3] = {d0, d1, d2};

  // Level 4 (uses OLD a1,a2,a3)
  float Z[3], Y[9], X[27];
#pragma unroll
  for (int i = 0; i < 3; i++) Z[i] = fmaf(d[i], 1.0f / 24.0f, (1.0f / 6.0f) * a1[i]);
#pragma unroll
  for (int e = 0; e < 9; e++) Y[e] = fmaf(d[e % 3], Z[e / 3], 0.5f * a2[e]);
#pragma unroll
  for (int e = 0; e < 27; e++) X[e] = fmaf(d[e % 3], Y[e / 3], a3[e]);
#pragma unroll
  for (int e = 0; e < 81; e++) a4[e] = fmaf(d[e % 3], X[e / 3], a4[e]);

  // Level 3 (uses OLD a1,a2)
  float Z3[3], Y3[9];
#pragma unroll
  for (int i = 0; i < 3; i++) Z3[i] = fmaf(d[i], 1.0f / 6.0f, 0.5f * a1[i]);
#pragma unroll
  for (int e = 0; e < 9; e++) Y3[e] = fmaf(d[e % 3], Z3[e / 3], a2[e]);
#pragma unroll
  for (int e = 0; e < 27; e++) a3[e] = fmaf(d[e % 3], Y3[e / 3], a3[e]);

  // Level 2 (uses OLD a1)
  float Z2[3];
#pragma unroll
  for (int i = 0; i < 3; i++) Z2[i] = fmaf(d[i], 0.5f, a1[i]);
#pragma unroll
  for (int e = 0; e < 9; e++) a2[e] = fmaf(d[e % 3], Z2[e / 3], a2[e]);

#pragma unroll
  for (int i = 0; i < 3; i++) a1[i] += d[i];
}

// ---------------------------------------------------------------------------
// Cross-lane fetch for the Chen combine.
//   OFF < 16 : DPP row_shl:OFF -> lane i reads lane i+OFF within its 16-lane
//              row; out-of-row lanes get 0 (= Chen identity). VALU pipe.
//   OFF >= 16: __shfl_xor butterfly (VERIFIED R2/R3/R5/R6). Only lane 0's
//              chain is consumed; its partners (lane 16 pre-round, lane 32
//              post-round-16) are always valid suffix products.
// ---------------------------------------------------------------------------
template <int OFF>
__device__ __forceinline__ float lane_down(float x) {
  if constexpr (OFF < 16) {
    return __int_as_float(__builtin_amdgcn_update_dpp(
        0, __float_as_int(x), 0x100 + OFF /*row_shl:OFF*/, 0xF, 0xF, true));
  } else {
    return __shfl_xor(x, OFF);
  }
}

// One Chen-combine round: state <- state (x) fetched-state.
template <int OFF>
__device__ __forceinline__ void chen_round(float a1[3], float a2[9], float a3[27], float a4[81]) {
  float B1[3], B2[9], B3[27];
#pragma unroll
  for (int i = 0; i < 3; i++) B1[i] = lane_down<OFF>(a1[i]);
#pragma unroll
  for (int i = 0; i < 9; i++) B2[i] = lane_down<OFF>(a2[i]);
#pragma unroll
  for (int i = 0; i < 27; i++) B3[i] = lane_down<OFF>(a3[i]);

#pragma unroll
  for (int e = 0; e < 81; e++) {
    const float b4 = lane_down<OFF>(a4[e]);  // reads pre-update a4[e]
    float v = a4[e] + b4;
    v = fmaf(a3[e / 3], B1[e % 3], v);
    v = fmaf(a2[e / 9], B2[e % 9], v);
    v = fmaf(a1[e / 27], B3[e % 27], v);
    a4[e] = v;
  }
#pragma unroll
  for (int e = 0; e < 27; e++) {
    float v = a3[e] + B3[e];
    v = fmaf(a2[e / 3], B1[e % 3], v);
    v = fmaf(a1[e / 9], B2[e % 9], v);
    a3[e] = v;
  }
#pragma unroll
  for (int e = 0; e < 9; e++) a2[e] = fmaf(a1[e / 3], B1[e % 3], a2[e] + B2[e]);
#pragma unroll
  for (int i = 0; i < 3; i++) a1[i] += B1[i];
}

// ---------------------------------------------------------------------------
// Kernel 1: signatures, reading inp directly (no transpose stage).
// inp layout: (B, C, T, V*M) -> element ((b*3+c)*300 + t)*34 + vm.
// Per-lane loads are strided but inp is 9.8 MB (LLC-resident) and the kernel
// is VALU-bound — load latency hides under ~4000 cycles of arithmetic.
// One PATH per WAVE (2176 one-wave blocks, ~2.1 waves/SIMD grid).
// 64 lanes x 5 Horner appends, then the Chen combine: 4 DPP row rounds
// (off 1,2,4,8) + 2 maskless __shfl_xor butterfly rounds (off 16,32).
// t-indices clamped to 299; invalid segments get d=0 (identity).
// First 512 blocks zero their ht row (b1 folded into gemm2).
// Output TRANSPOSED: St[k][b], k = vm*120 + c.
// ---------------------------------------------------------------------------
__global__ __launch_bounds__(64)
__attribute__((amdgpu_waves_per_eu(1)))
void sig_kernel(const float* __restrict__ inp, float* __restrict__ St,
                float* __restrict__ ht) {
  const int lane = threadIdx.x & 63;
  const int p = blockIdx.x;         // 2176 paths
  if (p < H1) ht[(size_t)p * 64 + lane] = 0.0f;  // zero-init for gemm1 atomics

  const int b = p / VM;
  const int vm = p - b * VM;
  const int t0 = lane * CHUNK;

  // base points at (b, c=0, t=0, vm); channel stride = T_PTS*VM = 10200,
  // t stride = VM = 34 (floats).
  const float* base = inp + (size_t)b * 3 * T_PTS * VM + vm;

  // Clamped point indices for this lane's 6 points.
  int tv[CHUNK + 1];
#pragma unroll
  for (int s = 0; s <= CHUNK; s++) {
    const int t = t0 + s;
    tv[s] = t < N_SEG ? t : N_SEG;
  }

  float a1[3], a2[9], a3[27], a4[81];
#pragma unroll
  for (int i = 0; i < 3; i++) a1[i] = 0.f;
#pragma unroll
  for (int i = 0; i < 9; i++) a2[i] = 0.f;
#pragma unroll
  for (int i = 0; i < 27; i++) a3[i] = 0.f;
#pragma unroll
  for (int i = 0; i < 81; i++) a4[i] = 0.f;

  float x0 = base[0 * T_PTS * VM + tv[0] * VM];
  float x1 = base[1 * T_PTS * VM + tv[0] * VM];
  float x2 = base[2 * T_PTS * VM + tv[0] * VM];
#pragma unroll
  for (int s = 0; s < CHUNK; s++) {
    const float y0 = base[0 * T_PTS * VM + tv[s + 1] * VM];
    const float y1 = base[1 * T_PTS * VM + tv[s + 1] * VM];
    const float y2 = base[2 * T_PTS * VM + tv[s + 1] * VM];
    const bool valid = (t0 + s) < N_SEG;
    const float d0 = valid ? (y0 - x0) : 0.0f;
    const float d1 = valid ? (y1 - x1) : 0.0f;
    const float d2 = valid ? (y2 - x2) : 0.0f;
    sig_append(a1, a2, a3, a4, d0, d1, d2);
    x0 = y0; x1 = y1; x2 = y2;
  }

  // Row-local suffix Chen product (16-lane Kogge-Stone via DPP).
  chen_round<1>(a1, a2, a3, a4);
  chen_round<2>(a1, a2, a3, a4);
  chen_round<4>(a1, a2, a3, a4);
  chen_round<8>(a1, a2, a3, a4);
  // Cross-row butterfly: lane 0 <- S(0..31) <- S(0..63).
  chen_round<16>(a1, a2, a3, a4);
  chen_round<32>(a1, a2, a3, a4);

  if (lane == 0) {
    float* dst = St + (size_t)(vm * SIGC) * 64 + b;  // St[(vm*120+i)*64 + b]
#pragma unroll
    for (int i = 0; i < 3; i++) dst[(size_t)i * 64] = a1[i];
#pragma unroll
    for (int i = 0; i < 9; i++) dst[(size_t)(3 + i) * 64] = a2[i];
#pragma unroll
    for (int i = 0; i < 27; i++) dst[(size_t)(12 + i) * 64] = a3[i];
#pragma unroll
    for (int i = 0; i < 81; i++) dst[(size_t)(39 + i) * 64] = a4[i];
  }
}

// ---------------------------------------------------------------------------
// Kernel 2: ht[j][b] += sum_k St[k][b] * W1[j][k].  lane = b (M=64=wave).
// 3072 waves: 48 K-splits (85 k each) x 64 j-groups (8 j each). sv[85]
// register-resident (static indices); W1 rows are wave-uniform streams
// (scalar loads). 8 independent FMA chains. Coalesced atomicAdd epilogue
// onto the zero-initialized ht (48 adds/element, order-independent).
// ---------------------------------------------------------------------------
__global__ __launch_bounds__(256) void gemm1_kernel(const float* __restrict__ St,
                                                    const float* __restrict__ W1,
                                                    float* __restrict__ ht) {
  const int lane = threadIdx.x & 63;
  int wave_id = (blockIdx.x * 256 + threadIdx.x) >> 6;        // 0..3071
  wave_id = __builtin_amdgcn_readfirstlane(wave_id);          // force SGPR
  const int ks = wave_id >> 6;    // 0..47  (k-range of 85)
  const int jg = wave_id & 63;    // 0..63  (8 j's each)
  const int k0 = ks * KW;

  const float* stp = St + (size_t)k0 * 64 + lane;
  const float* w[JPW];
#pragma unroll
  for (int r = 0; r < JPW; r++) w[r] = W1 + (size_t)(jg * JPW + r) * FAN1 + k0;  // uniform -> s_load

  float sv[KW];
#pragma unroll
  for (int i = 0; i < KW; i++) sv[i] = stp[(size_t)i * 64];

  float acc[JPW];
#pragma unroll
  for (int r = 0; r < JPW; r++) acc[r] = 0.f;

#pragma unroll
  for (int i = 0; i < KW; i++) {
#pragma unroll
    for (int r = 0; r < JPW; r++) acc[r] = fmaf(sv[i], w[r][i], acc[r]);
  }

  float* hp = ht + (size_t)(jg * JPW) * 64 + lane;
#pragma unroll
  for (int r = 0; r < JPW; r++) atomicAdd(hp + r * 64, acc[r]);
}

// ---------------------------------------------------------------------------
// Kernel 3: out[b][j] = sum_k2 (ht[k2][b] + b1[k2]) * W2[j][k2] + b2[j].
// lane = b. Block = one j; 4 waves split k2 (128 each). The b1 fold is a
// second wave-uniform FMA chain in the same loop; red[w] = acc + accb so
// the LDS reduce also sums the b1·W2[j] correction. Single non-atomic store.
// ---------------------------------------------------------------------------
__global__ __launch_bounds__(256) void gemm2_kernel(const float* __restrict__ ht,
                                                    const float* __restrict__ W2,
                                                    const float* __restrict__ b1,
                                                    const float* __restrict__ b2,
                                                    float* __restrict__ out) {
  const int j = blockIdx.x;              // 0..154
  const int lane = threadIdx.x & 63;
  int w = threadIdx.x >> 6;              // 0..3
  w = __builtin_amdgcn_readfirstlane(w);
  __shared__ float red[4][64];

  const float* htp = ht + (size_t)(w * 128) * 64 + lane;
  const float* w2r = W2 + (size_t)j * H1 + w * 128;  // uniform -> s_load
  const float* b1r = b1 + w * 128;                   // uniform -> s_load
  float acc = 0.f, accb = 0.f;
#pragma unroll 8
  for (int k = 0; k < 128; k++) {
    const float wv = w2r[k];
    acc = fmaf(wv, htp[(size_t)k * 64], acc);
    accb = fmaf(wv, b1r[k], accb);
  }

  red[w][lane] = acc + accb;
  __syncthreads();
  if (threadIdx.x < 64) {
    const float tot = red[0][lane] + red[1][lane] + red[2][lane] + red[3][lane];
    out[(size_t)lane * NOUT + j] = tot + b2[j];
  }
}

// ---------------------------------------------------------------------------
extern "C" void kernel_launch(void* const* d_in, const int* in_sizes, int n_in,
                              void* d_out, int out_size, void* d_ws, size_t ws_size,
                              hipStream_t stream) {
  const float* inp = (const float*)d_in[0];  // (64,3,300,17,2)
  const float* W1  = (const float*)d_in[1];  // (512,4080)
  const float* b1  = (const float*)d_in[2];  // (512,)
  const float* W2  = (const float*)d_in[3];  // (155,512)
  const float* b2  = (const float*)d_in[4];  // (155,)
  float* out = (float*)d_out;                // (64,155)

  // ws layout (floats): St | ht   (~1.2 MB total)
  float* St = (float*)d_ws;                  // 4080*64
  float* ht = St + (size_t)FAN1 * 64;        // 512*64

  sig_kernel<<<NPATH, 64, 0, stream>>>(inp, St, ht);
  gemm1_kernel<<<KSPL * 64 / 4, 256, 0, stream>>>(St, W1, ht);
  gemm2_kernel<<<NOUT, 256, 0, stream>>>(ht, W2, b1, b2, out);
}

// Round 11
// 112.843 us; speedup vs baseline: 1.7528x; 1.0249x over previous
//
#include <hip/hip_runtime.h>
#include <hip/hip_bf16.h>

// Problem shapes
#define B_SZ 64
#define T_PTS 300
#define N_SEG 299        // number of segments
#define VM 34            // 17*2
#define NPATH (B_SZ*VM)  // 2176
#define SIGC 120         // 3+9+27+81
#define FAN1 4080        // 34*120
#define H1 512
#define NOUT 155
#define CHUNK 5          // segments per lane (64*5=320 >= 299, 7% waste)
#define KSPL 48          // gemm1 K-splits
#define KW 85            // k per wave (48*85 = 4080)
#define JPW 8            // gemm1 j-rows per wave
#define NXCD 8           // MI355X XCD count; NPATH = 8*272 exactly (bijective)

// ---------------------------------------------------------------------------
// SESSION JOURNAL (why this exact configuration):
//  R6/R10 = this config: 114.2 / 115.7 us (best band; R3 113.96 w/ transpose).
//  R7  coop-LDS-tree combine: 115.5 (neutral) -> shfl butterflies kept.
//  R8  amdgpu_waves_per_eu(3): allocator SPILLED the 120-float state
//      (VGPR 136->84, 400 MB scratch HBM, sig 138 us). NEVER raise it.
//  R9  2-wave/path split: sig 44.5 us vs ~33 here (+25% issues, +33% loads,
//      3 barriers). State too big to split without spill or redundant work.
//      ALSO measured: sig FETCH_SIZE 30.7 MB vs 9.8 MB inp = 3x over-fetch
//      from same-b blocks landing on different XCD L2s -> R11 XCD swizzle.
//  R4  v_permlane16/32_swap butterflies: WRONG DIRECTION (absmax 497).
//      Do not reintroduce without an isolated semantics probe.
//  R11 (this round): XCD-aware path swizzle p=(bid&7)*272+(bid>>3) so each
//      XCD owns 8 complete batches; 34 same-b blocks share one L2 slice.
// ---------------------------------------------------------------------------

// ---------------------------------------------------------------------------
// Absorb one linear segment with increment d into state a1..a4.
// Horner-factored (segment signature = exp(d)): 189 VALU ops vs ~480 naive.
// ---------------------------------------------------------------------------
__device__ __forceinline__ void sig_append(float a1[3], float a2[9], float a3[27], float a4[81],
                                           float d0, float d1, float d2) {
  const float d[3] = {d0, d1, d2};

  // Level 4 (uses OLD a1,a2,a3)
  float Z[3], Y[9], X[27];
#pragma unroll
  for (int i = 0; i < 3; i++) Z[i] = fmaf(d[i], 1.0f / 24.0f, (1.0f / 6.0f) * a1[i]);
#pragma unroll
  for (int e = 0; e < 9; e++) Y[e] = fmaf(d[e % 3], Z[e / 3], 0.5f * a2[e]);
#pragma unroll
  for (int e = 0; e < 27; e++) X[e] = fmaf(d[e % 3], Y[e / 3], a3[e]);
#pragma unroll
  for (int e = 0; e < 81; e++) a4[e] = fmaf(d[e % 3], X[e / 3], a4[e]);

  // Level 3 (uses OLD a1,a2)
  float Z3[3], Y3[9];
#pragma unroll
  for (int i = 0; i < 3; i++) Z3[i] = fmaf(d[i], 1.0f / 6.0f, 0.5f * a1[i]);
#pragma unroll
  for (int e = 0; e < 9; e++) Y3[e] = fmaf(d[e % 3], Z3[e / 3], a2[e]);
#pragma unroll
  for (int e = 0; e < 27; e++) a3[e] = fmaf(d[e % 3], Y3[e / 3], a3[e]);

  // Level 2 (uses OLD a1)
  float Z2[3];
#pragma unroll
  for (int i = 0; i < 3; i++) Z2[i] = fmaf(d[i], 0.5f, a1[i]);
#pragma unroll
  for (int e = 0; e < 9; e++) a2[e] = fmaf(d[e % 3], Z2[e / 3], a2[e]);

#pragma unroll
  for (int i = 0; i < 3; i++) a1[i] += d[i];
}

// ---------------------------------------------------------------------------
// Cross-lane fetch for the Chen combine.
//   OFF < 16 : DPP row_shl:OFF -> lane i reads lane i+OFF within its 16-lane
//              row; out-of-row lanes get 0 (= Chen identity). VALU pipe.
//   OFF >= 16: __shfl_xor butterfly (VERIFIED R2/R3/R5/R6/R10). Only lane
//              0's chain is consumed; its partners (lane 16 pre-round,
//              lane 32 post-round-16) are always valid suffix products.
// ---------------------------------------------------------------------------
template <int OFF>
__device__ __forceinline__ float lane_down(float x) {
  if constexpr (OFF < 16) {
    return __int_as_float(__builtin_amdgcn_update_dpp(
        0, __float_as_int(x), 0x100 + OFF /*row_shl:OFF*/, 0xF, 0xF, true));
  } else {
    return __shfl_xor(x, OFF);
  }
}

// One Chen-combine round: state <- state (x) fetched-state.
template <int OFF>
__device__ __forceinline__ void chen_round(float a1[3], float a2[9], float a3[27], float a4[81]) {
  float B1[3], B2[9], B3[27];
#pragma unroll
  for (int i = 0; i < 3; i++) B1[i] = lane_down<OFF>(a1[i]);
#pragma unroll
  for (int i = 0; i < 9; i++) B2[i] = lane_down<OFF>(a2[i]);
#pragma unroll
  for (int i = 0; i < 27; i++) B3[i] = lane_down<OFF>(a3[i]);

#pragma unroll
  for (int e = 0; e < 81; e++) {
    const float b4 = lane_down<OFF>(a4[e]);  // reads pre-update a4[e]
    float v = a4[e] + b4;
    v = fmaf(a3[e / 3], B1[e % 3], v);
    v = fmaf(a2[e / 9], B2[e % 9], v);
    v = fmaf(a1[e / 27], B3[e % 27], v);
    a4[e] = v;
  }
#pragma unroll
  for (int e = 0; e < 27; e++) {
    float v = a3[e] + B3[e];
    v = fmaf(a2[e / 3], B1[e % 3], v);
    v = fmaf(a1[e / 9], B2[e % 9], v);
    a3[e] = v;
  }
#pragma unroll
  for (int e = 0; e < 9; e++) a2[e] = fmaf(a1[e / 3], B1[e % 3], a2[e] + B2[e]);
#pragma unroll
  for (int i = 0; i < 3; i++) a1[i] += B1[i];
}

// ---------------------------------------------------------------------------
// Kernel 1: signatures, reading inp directly (no transpose stage).
// inp layout: (B, C, T, V*M) -> element ((b*3+c)*300 + t)*34 + vm.
// XCD SWIZZLE (R11): p = (bid&7)*272 + (bid>>3). bid%8 selects the XCD
// (round-robin dispatch), so XCD k processes the contiguous path range
// [272k, 272k+272) = batches b in [8k, 8k+8). All 34 same-b blocks run on
// ONE XCD -> the 122 KB b-slice is fetched into that L2 once, reused 33x
// (R9 measured 30.7 MB HBM fetch vs 9.8 MB inp = 3x over-fetch without it).
// One PATH per WAVE (2176 one-wave blocks). 64 lanes x 5 Horner appends,
// then Chen combine: 4 DPP row rounds + 2 shfl_xor butterfly rounds.
// t-indices clamped to 299; invalid segments get d=0 (identity).
// 512 of the blocks zero one ht row each (b1 folded into gemm2).
// Output TRANSPOSED: St[k][b], k = vm*120 + c.
// ---------------------------------------------------------------------------
__global__ __launch_bounds__(64)
__attribute__((amdgpu_waves_per_eu(1)))
void sig_kernel(const float* __restrict__ inp, float* __restrict__ St,
                float* __restrict__ ht) {
  const int lane = threadIdx.x & 63;
  const int bid = blockIdx.x;       // 0..2175
  const int p = (bid & (NXCD - 1)) * (NPATH / NXCD) + (bid >> 3);  // bijective
  if (p < H1) ht[(size_t)p * 64 + lane] = 0.0f;  // zero-init for gemm1 atomics

  const int b = p / VM;
  const int vm = p - b * VM;
  const int t0 = lane * CHUNK;

  // base points at (b, c=0, t=0, vm); channel stride = T_PTS*VM = 10200,
  // t stride = VM = 34 (floats).
  const float* base = inp + (size_t)b * 3 * T_PTS * VM + vm;

  // Clamped point indices for this lane's 6 points.
  int tv[CHUNK + 1];
#pragma unroll
  for (int s = 0; s <= CHUNK; s++) {
    const int t = t0 + s;
    tv[s] = t < N_SEG ? t : N_SEG;
  }

  float a1[3], a2[9], a3[27], a4[81];
#pragma unroll
  for (int i = 0; i < 3; i++) a1[i] = 0.f;
#pragma unroll
  for (int i = 0; i < 9; i++) a2[i] = 0.f;
#pragma unroll
  for (int i = 0; i < 27; i++) a3[i] = 0.f;
#pragma unroll
  for (int i = 0; i < 81; i++) a4[i] = 0.f;

  float x0 = base[0 * T_PTS * VM + tv[0] * VM];
  float x1 = base[1 * T_PTS * VM + tv[0] * VM];
  float x2 = base[2 * T_PTS * VM + tv[0] * VM];
#pragma unroll
  for (int s = 0; s < CHUNK; s++) {
    const float y0 = base[0 * T_PTS * VM + tv[s + 1] * VM];
    const float y1 = base[1 * T_PTS * VM + tv[s + 1] * VM];
    const float y2 = base[2 * T_PTS * VM + tv[s + 1] * VM];
    const bool valid = (t0 + s) < N_SEG;
    const float d0 = valid ? (y0 - x0) : 0.0f;
    const float d1 = valid ? (y1 - x1) : 0.0f;
    const float d2 = valid ? (y2 - x2) : 0.0f;
    sig_append(a1, a2, a3, a4, d0, d1, d2);
    x0 = y0; x1 = y1; x2 = y2;
  }

  // Row-local suffix Chen product (16-lane Kogge-Stone via DPP).
  chen_round<1>(a1, a2, a3, a4);
  chen_round<2>(a1, a2, a3, a4);
  chen_round<4>(a1, a2, a3, a4);
  chen_round<8>(a1, a2, a3, a4);
  // Cross-row butterfly: lane 0 <- S(0..31) <- S(0..63).
  chen_round<16>(a1, a2, a3, a4);
  chen_round<32>(a1, a2, a3, a4);

  if (lane == 0) {
    float* dst = St + (size_t)(vm * SIGC) * 64 + b;  // St[(vm*120+i)*64 + b]
#pragma unroll
    for (int i = 0; i < 3; i++) dst[(size_t)i * 64] = a1[i];
#pragma unroll
    for (int i = 0; i < 9; i++) dst[(size_t)(3 + i) * 64] = a2[i];
#pragma unroll
    for (int i = 0; i < 27; i++) dst[(size_t)(12 + i) * 64] = a3[i];
#pragma unroll
    for (int i = 0; i < 81; i++) dst[(size_t)(39 + i) * 64] = a4[i];
  }
}

// ---------------------------------------------------------------------------
// Kernel 2: ht[j][b] += sum_k St[k][b] * W1[j][k].  lane = b (M=64=wave).
// 3072 waves: 48 K-splits (85 k each) x 64 j-groups (8 j each). sv[85]
// register-resident (static indices); W1 rows are wave-uniform streams
// (scalar loads). 8 independent FMA chains. Coalesced atomicAdd epilogue
// onto the zero-initialized ht (48 adds/element, order-independent).
// ---------------------------------------------------------------------------
__global__ __launch_bounds__(256) void gemm1_kernel(const float* __restrict__ St,
                                                    const float* __restrict__ W1,
                                                    float* __restrict__ ht) {
  const int lane = threadIdx.x & 63;
  int wave_id = (blockIdx.x * 256 + threadIdx.x) >> 6;        // 0..3071
  wave_id = __builtin_amdgcn_readfirstlane(wave_id);          // force SGPR
  const int ks = wave_id >> 6;    // 0..47  (k-range of 85)
  const int jg = wave_id & 63;    // 0..63  (8 j's each)
  const int k0 = ks * KW;

  const float* stp = St + (size_t)k0 * 64 + lane;
  const float* w[JPW];
#pragma unroll
  for (int r = 0; r < JPW; r++) w[r] = W1 + (size_t)(jg * JPW + r) * FAN1 + k0;  // uniform -> s_load

  float sv[KW];
#pragma unroll
  for (int i = 0; i < KW; i++) sv[i] = stp[(size_t)i * 64];

  float acc[JPW];
#pragma unroll
  for (int r = 0; r < JPW; r++) acc[r] = 0.f;

#pragma unroll
  for (int i = 0; i < KW; i++) {
#pragma unroll
    for (int r = 0; r < JPW; r++) acc[r] = fmaf(sv[i], w[r][i], acc[r]);
  }

  float* hp = ht + (size_t)(jg * JPW) * 64 + lane;
#pragma unroll
  for (int r = 0; r < JPW; r++) atomicAdd(hp + r * 64, acc[r]);
}

// ---------------------------------------------------------------------------
// Kernel 3: out[b][j] = sum_k2 (ht[k2][b] + b1[k2]) * W2[j][k2] + b2[j].
// lane = b. Block = one j; 4 waves split k2 (128 each). The b1 fold is a
// second wave-uniform FMA chain in the same loop; red[w] = acc + accb so
// the LDS reduce also sums the b1·W2[j] correction. Single non-atomic store.
// ---------------------------------------------------------------------------
__global__ __launch_bounds__(256) void gemm2_kernel(const float* __restrict__ ht,
                                                    const float* __restrict__ W2,
                                                    const float* __restrict__ b1,
                                                    const float* __restrict__ b2,
                                                    float* __restrict__ out) {
  const int j = blockIdx.x;              // 0..154
  const int lane = threadIdx.x & 63;
  int w = threadIdx.x >> 6;              // 0..3
  w = __builtin_amdgcn_readfirstlane(w);
  __shared__ float red[4][64];

  const float* htp = ht + (size_t)(w * 128) * 64 + lane;
  const float* w2r = W2 + (size_t)j * H1 + w * 128;  // uniform -> s_load
  const float* b1r = b1 + w * 128;                   // uniform -> s_load
  float acc = 0.f, accb = 0.f;
#pragma unroll 8
  for (int k = 0; k < 128; k++) {
    const float wv = w2r[k];
    acc = fmaf(wv, htp[(size_t)k * 64], acc);
    accb = fmaf(wv, b1r[k], accb);
  }

  red[w][lane] = acc + accb;
  __syncthreads();
  if (threadIdx.x < 64) {
    const float tot = red[0][lane] + red[1][lane] + red[2][lane] + red[3][lane];
    out[(size_t)lane * NOUT + j] = tot + b2[j];
  }
}

// ---------------------------------------------------------------------------
extern "C" void kernel_launch(void* const* d_in, const int* in_sizes, int n_in,
                              void* d_out, int out_size, void* d_ws, size_t ws_size,
                              hipStream_t stream) {
  const float* inp = (const float*)d_in[0];  // (64,3,300,17,2)
  const float* W1  = (const float*)d_in[1];  // (512,4080)
  const float* b1  = (const float*)d_in[2];  // (512,)
  const float* W2  = (const float*)d_in[3];  // (155,512)
  const float* b2  = (const float*)d_in[4];  // (155,)
  float* out = (float*)d_out;                // (64,155)

  // ws layout (floats): St | ht   (~1.2 MB total)
  float* St = (float*)d_ws;                  // 4080*64
  float* ht = St + (size_t)FAN1 * 64;        // 512*64

  sig_kernel<<<NPATH, 64, 0, stream>>>(inp, St, ht);
  gemm1_kernel<<<KSPL * 64 / 4, 256, 0, stream>>>(St, W1, ht);
  gemm2_kernel<<<NOUT, 256, 0, stream>>>(ht, W2, b1, b2, out);
}